// Round 8
// baseline (310.729 us; speedup 1.0000x reference)
//
#include <hip/hip_runtime.h>
#include <math.h>

// GraphCritic: GCNConv (sym-norm + self-loops) -> per-column lower median ->
// tanh MLP -> scalar.
// v16: k_finalMlp select rewritten. v15's counters showed 41us with VALU 2%,
//      occ 3.4%, 50 GB/s: a latency kernel - 1 block/CU (no TLP) running a
//      rolled dependent loop {global u16 load -> LDS atomic} x56 iters x2
//      rounds, with round-0 loads cross-XCD (~900cy). Fix: register-resident
//      binary search - each thread loads its <=96 keys ONCE via unrolled
//      independent coalesced loads (pipelined latency), then 16 MSB-first
//      iterations of count(<pivot) via unrolled compares + shfl reduce +
//      4-entry LDS sum. Feasible set is a prefix interval -> greedy bit-build
//      = exact r-th order statistic (bit-identical to radix result).
//      Everything else identical to v15.

#define CAP    24576   // candidate capacity per column (expect ~14.3K)
#define MPT    96      // keys per thread in k_finalMlp (= CAP/256)
#define CCAP   96      // per-block per-column LDS candidate slots
#define CSTR   97      // buf column stride in halfs (bank-spread padding)
#define DSTR   32      // adjacency slots per node
#define OVCAP  4096    // overflow edge capacity (deg>32 spill, expect ~60)
#define SPCAP  2048    // spill node list capacity (expect ~15)
#define BCAP   4608    // edges per 256-node bucket (mean 4092, sd 64: +8 sigma)
#define NBKMAX 400
#define CH     4096    // bin chunk size

typedef __attribute__((ext_vector_type(8))) short short8;   // 8 bf16
typedef __attribute__((ext_vector_type(4))) float f32x4;
typedef __attribute__((ext_vector_type(8))) _Float16 half8;
typedef __attribute__((ext_vector_type(2))) _Float16 half2v;

__device__ __forceinline__ unsigned ordKey(float x) {
    unsigned u = __float_as_uint(x);
    return (u & 0x80000000u) ? ~u : (u | 0x80000000u);
}
__device__ __forceinline__ unsigned short f2bf(float f) {   // RNE
    unsigned u = __float_as_uint(f);
    return (unsigned short)((u + 0x7FFFu + ((u >> 16) & 1u)) >> 16);
}

// ---------------- init: zero counters; W -> frag layout --------------------
__global__ void k_init(int* __restrict__ cursor, int* __restrict__ below,
                       int* __restrict__ candCnt, int* __restrict__ ovCnt,
                       const float* __restrict__ W, short* __restrict__ Whi,
                       short* __restrict__ Wlo, int nbk) {
    if (blockIdx.x == 1) {
        for (int idx = threadIdx.x; idx < 16384; idx += 256) {
            int j = idx & 7, lane = (idx >> 3) & 63;
            int t = (idx >> 9) & 7, s = idx >> 12;
            int row = t * 16 + (lane & 15);
            int k = s * 32 + (lane >> 4) * 8 + j;
            float w = W[row * 128 + k];
            unsigned short hb = f2bf(w);
            float hf = __uint_as_float((unsigned)hb << 16);
            Whi[idx] = (short)hb;
            Wlo[idx] = (short)f2bf(w - hf);
        }
        return;
    }
    int t = threadIdx.x;
    for (int i = t; i < nbk; i += 256) cursor[i] = 0;
    if (t < 128) { below[t] = 0; candCnt[t] = 0; }
    if (t == 0) { ovCnt[0] = 0; ovCnt[1] = 0; ovCnt[2] = 0; }
}

// ---------------- GEMM: xw = x @ W^T (split-bf16 MFMA, fp16 out) ----------
__global__ __launch_bounds__(256) void k_gemm(
        const float* __restrict__ x, const short* __restrict__ Whi,
        const short* __restrict__ Wlo, _Float16* __restrict__ xw, int n) {
    __shared__ float trn[4 * 16 * 132];            // 33.8 KB
    const int t = threadIdx.x;
    const int lane = t & 63, wv = t >> 6;
    const int quad = lane >> 4, m = lane & 15;
    const int rowBase = blockIdx.x * 64 + wv * 16;
    const int r = rowBase + m;
    const int rl = r < n ? r : (n - 1);
    f32x4 acc[8];
    #pragma unroll
    for (int q = 0; q < 8; q++) acc[q] = (f32x4){0.f, 0.f, 0.f, 0.f};
    #pragma unroll
    for (int s = 0; s < 4; s++) {
        const float* xp = x + (size_t)rl * 128 + s * 32 + quad * 8;
        float4 p0 = *(const float4*)xp;
        float4 p1 = *(const float4*)(xp + 4);
        float f[8] = {p0.x, p0.y, p0.z, p0.w, p1.x, p1.y, p1.z, p1.w};
        short8 ah, al;
        #pragma unroll
        for (int j = 0; j < 8; j++) {
            unsigned short hb = f2bf(f[j]);
            float hf = __uint_as_float((unsigned)hb << 16);
            ah[j] = (short)hb;
            al[j] = (short)f2bf(f[j] - hf);
        }
        #pragma unroll
        for (int q = 0; q < 8; q++) {
            short8 bh = *(const short8*)(Whi + (((s * 8 + q) * 64 + lane) << 3));
            short8 bl = *(const short8*)(Wlo + (((s * 8 + q) * 64 + lane) << 3));
            acc[q] = __builtin_amdgcn_mfma_f32_16x16x32_bf16(ah, bh, acc[q], 0, 0, 0);
            acc[q] = __builtin_amdgcn_mfma_f32_16x16x32_bf16(al, bh, acc[q], 0, 0, 0);
            acc[q] = __builtin_amdgcn_mfma_f32_16x16x32_bf16(ah, bl, acc[q], 0, 0, 0);
        }
    }
    float* tw = trn + wv * (16 * 132);
    #pragma unroll
    for (int q = 0; q < 8; q++)
        #pragma unroll
        for (int e = 0; e < 4; e++)
            tw[(quad * 4 + e) * 132 + q * 16 + m] = acc[q][e];
    // wave-private ds_write->ds_read ordered by lgkmcnt: no barrier
    #pragma unroll
    for (int i = 0; i < 4; i++) {
        int row = i * 4 + (lane >> 4);
        int c8 = lane & 15;
        const float* tp = tw + row * 132 + c8 * 8;
        float4 p0 = *(const float4*)tp;
        float4 p1 = *(const float4*)(tp + 4);
        half8 o;
        o[0] = (_Float16)p0.x; o[1] = (_Float16)p0.y;
        o[2] = (_Float16)p0.z; o[3] = (_Float16)p0.w;
        o[4] = (_Float16)p1.x; o[5] = (_Float16)p1.y;
        o[6] = (_Float16)p1.z; o[7] = (_Float16)p1.w;
        int grow = rowBase + row;
        if (grow < n) *(half8*)(xw + (size_t)grow * 128 + c8 * 8) = o;
    }
}

// ---------------- BIN: chunked LDS binning of edges by dst bucket ---------
__global__ __launch_bounds__(256) void k_bin(
        const int* __restrict__ src, const int* __restrict__ dst, int E,
        int* __restrict__ cursor, int2* __restrict__ binned,
        int* __restrict__ ovCnt, int2* __restrict__ ovBuf, int nbk) {
    __shared__ char smem[39168];
    const int t = threadIdx.x;
    int2* stage = (int2*)smem;                 // 32 KB
    int* hist  = (int*)(smem + 32768);
    int* gbase = hist + NBKMAX;
    int* hist2 = gbase + NBKMAX;
    int* sbase = hist2 + NBKMAX;
    const int e0 = (int)blockIdx.x * CH;
    const int len = min(CH, E - e0);
    for (int i = t; i < nbk; i += 256) { hist[i] = 0; hist2[i] = 0; }
    __syncthreads();
    for (int k = t; k < len; k += 256) {
        int s = src[e0 + k], d = dst[e0 + k];
        stage[k] = make_int2(s, d);
        atomicAdd(&hist[d >> 8], 1);
    }
    __syncthreads();
    for (int i = t; i < nbk; i += 256) {
        int c = hist[i];
        if (c) {
            int g = atomicAdd(&cursor[i], c);
            if (g + c <= BCAP) gbase[i] = g;
            else {                              // p ~ 1e-13: spill chunk
                gbase[i] = -1;
                sbase[i] = atomicAdd(ovCnt, c);
            }
        }
    }
    __syncthreads();
    for (int k = t; k < len; k += 256) {
        int2 e = stage[k];
        int b = e.y >> 8;
        int p = atomicAdd(&hist2[b], 1);
        int g = gbase[b];
        if (g >= 0) binned[(size_t)b * BCAP + g + p] = e;
        else {
            int o = sbase[b] + p;
            if (o < OVCAP) ovBuf[o] = make_int2(e.y, e.x);
        }
    }
}

// ---------------- build: single-pass LDS adjacency + coalesced dump -------
__global__ __launch_bounds__(512) void k_build(int2* __restrict__ binned,
                                               const int* __restrict__ cursor,
                                               float* __restrict__ dinv,
                                               unsigned char* __restrict__ deg8,
                                               int* __restrict__ ovCnt,
                                               int2* __restrict__ ovBuf,
                                               int* __restrict__ spillNodes, int n) {
    __shared__ int ladj[256 * DSTR];               // 32 KB
    __shared__ int lcnt[256];
    const int b = blockIdx.x, t = threadIdx.x;
    const int cnt = min(cursor[b], BCAP);
    const size_t e0 = (size_t)b * BCAP;
    if (t < 256) lcnt[t] = 0;
    __syncthreads();
    for (int k = t; k < cnt; k += 512) {
        int2 e = binned[e0 + k];                   // (src, dst)
        int li = e.y & 255;
        int pos = atomicAdd(&lcnt[li], 1);
        if (pos < DSTR) ladj[li * DSTR + pos] = e.x;
        else {
            int o = atomicAdd(ovCnt, 1);
            if (o < OVCAP) ovBuf[o] = make_int2(e.y, e.x);
        }
    }
    __syncthreads();
    int4* adjOut = (int4*)((int*)binned + e0 * 2);
    const int4* lsrc4 = (const int4*)ladj;
    for (int i = t; i < 2048; i += 512) adjOut[i] = lsrc4[i];
    if (t < 256) {
        int node = b * 256 + t;
        if (node < n) {
            int deg = lcnt[t];
            dinv[node] = (float)(1.0 / sqrt((double)(deg + 1)));
            deg8[node] = (unsigned char)(deg < 255 ? deg : 255);   // true degree
            if (deg > DSTR) {
                int p = atomicAdd(ovCnt + 1, 1);                   // spillCnt
                if (p < SPCAP) spillNodes[p] = node;
            }
        }
    }
}

// ---------------- main aggregation: 1 node/wave, pure gather, fp16 h ------
// Half-range launch (diagnostic split): d in [n0, n1).
__global__ __launch_bounds__(256) void k_aggH(const _Float16* __restrict__ xw,
                                              const unsigned char* __restrict__ deg8,
                                              const int* __restrict__ adjAll,
                                              const float* __restrict__ dinv,
                                              const float* __restrict__ conv_b,
                                              _Float16* __restrict__ h,
                                              int n0, int n1) {
    const int d = n0 + blockIdx.x * 4 + (threadIdx.x >> 6);
    if (d >= n1) return;
    const int lane = threadIdx.x & 63;
    const int l32 = lane & 31;
    int degT = deg8[d];
    const int degB = degT < DSTR ? degT : DSTR;    // spill rows fixed later
    const float dd = dinv[d];
    const int* adjRow = adjAll + (size_t)(d >> 8) * (BCAP * 2) + (d & 255) * DSTR;
    int aj = adjRow[l32];
    bool ev = (lane < 32) && (l32 < degB);
    int ajs = ev ? aj : 0;
    float dv = ev ? dinv[ajs] : 0.f;
    const half2v* xwv = (const half2v*)xw;
    half2v a = xwv[(size_t)d * 64 + lane];
    float ax = dd * dd * (float)a.x, ay = dd * dd * (float)a.y;   // self-loop
    int j = 0;
    for (; j + 8 <= degB; j += 8) {
        int s[8];
        float w[8];
        #pragma unroll
        for (int q = 0; q < 8; q++) {
            s[q] = __shfl(ajs, j + q, 64);
            w[q] = dd * __shfl(dv, j + q, 64);
        }
        #pragma unroll
        for (int q = 0; q < 8; q++) {
            half2v v = xwv[(size_t)s[q] * 64 + lane];
            ax += w[q] * (float)v.x;
            ay += w[q] * (float)v.y;
        }
    }
    if (j < degB) {
        int s[8];
        float w[8];
        #pragma unroll
        for (int q = 0; q < 8; q++) {
            int idx = j + q;
            bool ok = idx < degB;
            int lsrc = ok ? idx : 0;
            int sv = __shfl(ajs, lsrc, 64);
            float wv = dd * __shfl(dv, lsrc, 64);
            s[q] = ok ? sv : 0;
            w[q] = ok ? wv : 0.f;
        }
        #pragma unroll
        for (int q = 0; q < 8; q++) {
            half2v v = xwv[(size_t)s[q] * 64 + lane];
            ax += w[q] * (float)v.x;
            ay += w[q] * (float)v.y;
        }
    }
    float2 cb = ((const float2*)conv_b)[lane];
    half2v o;
    o.x = (_Float16)(ax + cb.x);
    o.y = (_Float16)(ay + cb.y);
    ((half2v*)h)[(size_t)d * 64 + lane] = o;
}

// ---------------- fused: sampled bracket (blocks 0-127) || spill fix ------
// Sample tolerates <=1 stale sampled row (expected 0.5/3125; 8-sigma bracket
// margin). Classify reads post-fix h, so below/cand stay exact.
__global__ __launch_bounds__(256) void k_sampleSpill(
        _Float16* h, int n,
        unsigned* __restrict__ Lkey, unsigned* __restrict__ Ukey,
        const _Float16* __restrict__ xw, const int* __restrict__ spillNodes,
        const int* __restrict__ adjAll, const float* __restrict__ dinv,
        const float* __restrict__ conv_b, const int2* __restrict__ ovBuf,
        const int* __restrict__ ovCnt) {
    const int t = threadIdx.x;
    if (blockIdx.x >= 128) {
        // ---- spill-fix role (16 blocks, threads 0-127) ----
        int m = ovCnt[0];  if (m > OVCAP) m = OVCAP;
        int sp = ovCnt[1]; if (sp > SPCAP) sp = SPCAP;
        if (t >= 128) return;
        for (int i = (int)blockIdx.x - 128; i < sp; i += 16) {
            const int d = spillNodes[i];
            const float dd = dinv[d];
            float acc = dd * dd * (float)xw[(size_t)d * 128 + t];
            const int* adjRow = adjAll + (size_t)(d >> 8) * (BCAP * 2) + (d & 255) * DSTR;
            for (int j = 0; j < DSTR; j++) {
                int a = adjRow[j];
                acc += dd * dinv[a] * (float)xw[(size_t)a * 128 + t];
            }
            for (int k = 0; k < m; k++) {
                int2 e = ovBuf[k];                 // (dst, src)
                if (e.x == d)
                    acc += dd * dinv[e.y] * (float)xw[(size_t)e.y * 128 + t];
            }
            h[(size_t)d * 128 + t] = (_Float16)(acc + conv_b[t]);
        }
        return;
    }
    // ---- sample role (128 blocks, one column each) ----
    __shared__ int hist[2048];
    __shared__ int wsum[4];
    const int c = blockIdx.x;
    for (int i = t; i < 2048; i += 256) hist[i] = 0;
    __syncthreads();
    const int ns = (n + 31) >> 5;
    for (int i = t; i < ns; i += 256) {
        float v = (float)h[(size_t)(i << 5) * 128 + c];
        atomicAdd(&hist[ordKey(v) >> 21], 1);
    }
    __syncthreads();
    int ps = 0;
    #pragma unroll
    for (int b = 0; b < 8; b++) ps += hist[t * 8 + b];
    const int lane = t & 63, wv = t >> 6;
    int sc = ps;
    #pragma unroll
    for (int off = 1; off < 64; off <<= 1) {
        int y = __shfl_up(sc, off, 64);
        if (lane >= off) sc += y;
    }
    if (lane == 63) wsum[wv] = sc;
    __syncthreads();
    int wbase = 0;
    for (int ww = 0; ww < wv; ww++) wbase += wsum[ww];
    const int excl = wbase + sc - ps;
    const int sMid = (ns - 1) >> 1;
    const int delta = (int)(4.0f * sqrtf((float)ns)) + 1;
    int sLo = sMid - delta; if (sLo < 0) sLo = 0;
    int sHi = sMid + delta; if (sHi > ns - 1) sHi = ns - 1;
    if (sLo >= excl && sLo < excl + ps) {
        int rem = sLo - excl, b = t * 8;
        for (;; b++) { int cc = hist[b]; if (rem < cc) break; rem -= cc; }
        Lkey[c] = (unsigned)b << 21;
    }
    if (sHi >= excl && sHi < excl + ps) {
        int rem = sHi - excl, b = t * 8;
        for (;; b++) { int cc = hist[b]; if (rem < cc) break; rem -= cc; }
        Ukey[c] = (((unsigned)(b + 1)) << 21) - 1u;
    }
}

// ---------------- classify: stream fp16 h, below-count + fp16 candidates --
// 512 blocks: 12 iters/thread; flush chains 512 deep. jb invariant:
// stride*8 = 512*256*8 multiple of 128.
__global__ __launch_bounds__(256) void k_classify(const _Float16* __restrict__ h,
                                                  int total8,
                                                  const unsigned* __restrict__ Lkey,
                                                  const unsigned* __restrict__ Ukey,
                                                  int* __restrict__ below,
                                                  int* __restrict__ candCnt,
                                                  _Float16* __restrict__ cand) {
    __shared__ _Float16 buf[128 * CSTR];  // 24.25 KB, stride 97 (bank-spread)
    __shared__ int cN[128], cB[128];
    const int t = threadIdx.x;
    for (int i = t; i < 128; i += 256) { cN[i] = 0; cB[i] = 0; }
    __syncthreads();
    const int stride = gridDim.x * blockDim.x;
    const int i0 = blockIdx.x * blockDim.x + t;
    const int jb = (i0 << 3) & 127;     // stride*8 % 128 == 0 -> invariant
    unsigned L[8], U[8];
    #pragma unroll
    for (int k = 0; k < 8; k++) { L[k] = Lkey[jb + k]; U[k] = Ukey[jb + k]; }
    int b[8] = {0, 0, 0, 0, 0, 0, 0, 0};
    const half8* hv = (const half8*)h;
    for (int i = i0; i < total8; i += stride) {
        half8 v = hv[i];
        #pragma unroll
        for (int k = 0; k < 8; k++) {
            float f = (float)v[k];
            unsigned u = ordKey(f);
            if (u < L[k]) b[k]++;
            else if (u <= U[k]) {
                int p = atomicAdd(&cN[jb + k], 1);
                if (p < CCAP) buf[(jb + k) * CSTR + p] = v[k];
                else {
                    int g = atomicAdd(&candCnt[jb + k], 1);
                    if (g < CAP) cand[(size_t)(jb + k) * CAP + g] = v[k];
                }
            }
        }
    }
    #pragma unroll
    for (int k = 0; k < 8; k++)
        if (b[k]) atomicAdd(&cB[jb + k], b[k]);
    __syncthreads();
    if (t < 128) {
        if (cB[t]) atomicAdd(&below[t], cB[t]);
        int nn = cN[t] < CCAP ? cN[t] : CCAP;
        if (nn) {
            int base = atomicAdd(&candCnt[t], nn);
            for (int k2 = 0; k2 < nn && base + k2 < CAP; k2++)
                cand[(size_t)t * CAP + base + k2] = buf[t * CSTR + k2];
        }
    }
}

// ---------------- final: register-resident binary-search select + MLP -----
// Each thread holds <=MPT keys in registers (one unrolled coalesced load
// phase), then 16 MSB-first iterations of count(<pivot): unrolled compares
// + wave shfl reduce + 4-entry LDS sum. Greedy bit-build over the prefix
// feasible set = exact r-th order statistic.
__global__ __launch_bounds__(256) void k_finalMlp(
        const _Float16* __restrict__ cand, const int* __restrict__ candCnt,
        const int* __restrict__ below, int n, float* __restrict__ med,
        int* __restrict__ doneCnt,
        const float* __restrict__ w1, const float* __restrict__ b1,
        const float* __restrict__ w2, const float* __restrict__ b2,
        const float* __restrict__ w3, const float* __restrict__ b3,
        float* __restrict__ out) {
    __shared__ int wsum[4];
    __shared__ int lastFlag;
    const int c = blockIdx.x, t = threadIdx.x;
    const int lane = t & 63, wv = t >> 6;
    int cnt = candCnt[c]; if (cnt > CAP) cnt = CAP;
    const unsigned short* cp = (const unsigned short*)cand + (size_t)c * CAP;
    int r = (n - 1) / 2 - below[c];
    if (r < 0) r = 0;
    if (r >= cnt) r = cnt - 1;
    // load phase: independent unrolled coalesced loads -> registers
    unsigned short myk[MPT];
    #pragma unroll
    for (int mi = 0; mi < MPT; mi++) {
        int i = t + mi * 256;
        unsigned ub = (i < cnt) ? (unsigned)cp[i] : 0u;
        unsigned k = (ub & 0x8000u) ? (~ub & 0xFFFFu) : (ub | 0x8000u);
        myk[mi] = (i < cnt) ? (unsigned short)k : (unsigned short)0xFFFFu;
    }
    // 16-iteration binary search on the 16-bit ordered-key space
    unsigned cur = 0;
    for (int bit = 15; bit >= 0; bit--) {
        const unsigned pivot = cur | (1u << bit);
        int lc = 0;
        #pragma unroll
        for (int mi = 0; mi < MPT; mi++) lc += ((unsigned)myk[mi] < pivot) ? 1 : 0;
        #pragma unroll
        for (int off = 32; off > 0; off >>= 1) lc += __shfl_down(lc, off, 64);
        if (lane == 0) wsum[wv] = lc;
        __syncthreads();
        int tot = wsum[0] + wsum[1] + wsum[2] + wsum[3];
        if (tot <= r) cur = pivot;                 // uniform across block
        __syncthreads();
    }
    if (t == 0) {
        unsigned short bits = (cur & 0x8000u) ? (unsigned short)(cur & 0x7FFFu)
                                              : (unsigned short)(~cur & 0xFFFFu);
        _Float16 hv;
        *(unsigned short*)&hv = bits;
        med[c] = (float)hv;
        __threadfence();
        int old = atomicAdd(doneCnt, 1);
        lastFlag = (old == 127);
    }
    __syncthreads();
    if (!lastFlag) return;
    __threadfence();                                // acquire all med writes
    // ---- MLP role (one block) ----
    __shared__ float m[128], a1[64], a2[64];
    if (t < 128) m[t] = med[t];
    __syncthreads();
    if (t < 64) {
        float acc = b1[t];
        for (int f = 0; f < 128; f++) acc += m[f] * w1[t * 128 + f];
        a1[t] = tanhf(acc);
    }
    __syncthreads();
    if (t < 64) {
        float acc = b2[t];
        for (int f = 0; f < 64; f++) acc += a1[f] * w2[t * 64 + f];
        a2[t] = tanhf(acc);
    }
    __syncthreads();
    if (t == 0) {
        float acc = b3[0];
        for (int f = 0; f < 64; f++) acc += a2[f] * w3[f];
        out[0] = acc;
    }
}

extern "C" void kernel_launch(void* const* d_in, const int* in_sizes, int n_in,
                              void* d_out, int out_size, void* d_ws, size_t ws_size,
                              hipStream_t stream) {
    const float* x      = (const float*)d_in[0];
    const int*   ei     = (const int*)d_in[1];
    const float* conv_W = (const float*)d_in[2];
    const float* conv_b = (const float*)d_in[3];
    const float* w1 = (const float*)d_in[4];
    const float* b1 = (const float*)d_in[5];
    const float* w2 = (const float*)d_in[6];
    const float* b2 = (const float*)d_in[7];
    const float* w3 = (const float*)d_in[8];
    const float* b3 = (const float*)d_in[9];

    const int N = in_sizes[0] / 128;
    const int E = in_sizes[1] / 2;
    const int* src = ei;
    const int* dst = ei + E;
    const int NBK = (N + 255) / 256;

    char* p = (char*)d_ws;
    auto alloc = [&](size_t bytes) -> char* {
        char* q = p;
        p += (bytes + 255) & ~(size_t)255;
        return q;
    };
    _Float16* xw  = (_Float16*)alloc((size_t)N * 128 * 2);  // fp16
    _Float16* h   = (_Float16*)alloc((size_t)N * 128 * 2);  // fp16
    int2*  binned = (int2*)alloc((size_t)NBK * BCAP * 8);   // 14.4 MB; becomes adj
    _Float16* cand = (_Float16*)alloc((size_t)128 * CAP * 2);  // 6.3 MB fp16
    float* dinv   = (float*)alloc((size_t)N * 4);
    unsigned char* deg8 = (unsigned char*)alloc((size_t)N);
    int*   cursor = (int*)alloc((size_t)NBK * 4);
    short* Whi    = (short*)alloc(16384 * 2);
    short* Wlo    = (short*)alloc(16384 * 2);
    int2*  ovBuf  = (int2*)alloc((size_t)OVCAP * 8);
    int*   ovCnt  = (int*)alloc(256);             // [0]=ov, [1]=spill, [2]=done
    int*   spillNodes = (int*)alloc((size_t)SPCAP * 4);
    unsigned* Lkey = (unsigned*)alloc(128 * 4);
    unsigned* Ukey = (unsigned*)alloc(128 * 4);
    int*   below   = (int*)alloc(128 * 4);
    int*   candCnt = (int*)alloc(128 * 4);
    float* med     = (float*)alloc(128 * 4);

    const int GB   = (N + 63) / 64;          // gemm blocks
    const int BINB = (E + CH - 1) / CH;      // bin blocks
    const int NH   = ((N / 2) + 3) & ~3;     // agg half split (mult of 4)

    k_init<<<2, 256, 0, stream>>>(cursor, below, candCnt, ovCnt, conv_W, Whi, Wlo, NBK);
    k_gemm<<<GB, 256, 0, stream>>>(x, Whi, Wlo, xw, N);
    k_bin<<<BINB, 256, 0, stream>>>(src, dst, E, cursor, binned, ovCnt, ovBuf, NBK);
    k_build<<<NBK, 512, 0, stream>>>(binned, cursor, dinv, deg8, ovCnt, ovBuf,
                                     spillNodes, N);
    k_aggH<<<(NH + 3) / 4, 256, 0, stream>>>(xw, deg8, (const int*)binned, dinv,
                                             conv_b, h, 0, NH);
    k_aggH<<<(N - NH + 3) / 4, 256, 0, stream>>>(xw, deg8, (const int*)binned, dinv,
                                                 conv_b, h, NH, N);
    k_sampleSpill<<<144, 256, 0, stream>>>(h, N, Lkey, Ukey, xw, spillNodes,
                                           (const int*)binned, dinv, conv_b,
                                           ovBuf, ovCnt);
    k_classify<<<512, 256, 0, stream>>>(h, N * 16, Lkey, Ukey, below, candCnt, cand);
    k_finalMlp<<<128, 256, 0, stream>>>(cand, candCnt, below, N, med, ovCnt + 2,
                                        w1, b1, w2, b2, w3, b3, (float*)d_out);
}

// Round 9
// 299.853 us; speedup vs baseline: 1.0363x; 1.0363x over previous
//
#include <hip/hip_runtime.h>
#include <math.h>

// GraphCritic: GCNConv (sym-norm + self-loops) -> per-column lower median ->
// tanh MLP -> scalar.
// v17: k_finalMlp de-spilled. v16's register-resident select never got its
//      registers: myk[96] u16 needs ~96 VGPRs (no packing), allocator capped
//      at 64 -> array spilled to scratch -> 16 iterations x 96 serialized
//      scratch reloads = the same 45us latency wall. Fix: 1024 threads/block,
//      MPT=24 -> ~24 key VGPRs + working set, truly register-resident; 16
//      waves/block hide the one-time load latency. Search: 16 iters x (24
//      unrolled compares + shfl reduce + 16-entry LDS sum + barrier).
//      Everything else identical to v16.

#define CAP    24576   // candidate capacity per column (expect ~14.3K)
#define MPT    24      // keys per thread in k_finalMlp (= CAP/1024)
#define CCAP   96      // per-block per-column LDS candidate slots
#define CSTR   97      // buf column stride in halfs (bank-spread padding)
#define DSTR   32      // adjacency slots per node
#define OVCAP  4096    // overflow edge capacity (deg>32 spill, expect ~60)
#define SPCAP  2048    // spill node list capacity (expect ~15)
#define BCAP   4608    // edges per 256-node bucket (mean 4092, sd 64: +8 sigma)
#define NBKMAX 400
#define CH     4096    // bin chunk size

typedef __attribute__((ext_vector_type(8))) short short8;   // 8 bf16
typedef __attribute__((ext_vector_type(4))) float f32x4;
typedef __attribute__((ext_vector_type(8))) _Float16 half8;
typedef __attribute__((ext_vector_type(2))) _Float16 half2v;

__device__ __forceinline__ unsigned ordKey(float x) {
    unsigned u = __float_as_uint(x);
    return (u & 0x80000000u) ? ~u : (u | 0x80000000u);
}
__device__ __forceinline__ unsigned short f2bf(float f) {   // RNE
    unsigned u = __float_as_uint(f);
    return (unsigned short)((u + 0x7FFFu + ((u >> 16) & 1u)) >> 16);
}

// ---------------- init: zero counters; W -> frag layout --------------------
__global__ void k_init(int* __restrict__ cursor, int* __restrict__ below,
                       int* __restrict__ candCnt, int* __restrict__ ovCnt,
                       const float* __restrict__ W, short* __restrict__ Whi,
                       short* __restrict__ Wlo, int nbk) {
    if (blockIdx.x == 1) {
        for (int idx = threadIdx.x; idx < 16384; idx += 256) {
            int j = idx & 7, lane = (idx >> 3) & 63;
            int t = (idx >> 9) & 7, s = idx >> 12;
            int row = t * 16 + (lane & 15);
            int k = s * 32 + (lane >> 4) * 8 + j;
            float w = W[row * 128 + k];
            unsigned short hb = f2bf(w);
            float hf = __uint_as_float((unsigned)hb << 16);
            Whi[idx] = (short)hb;
            Wlo[idx] = (short)f2bf(w - hf);
        }
        return;
    }
    int t = threadIdx.x;
    for (int i = t; i < nbk; i += 256) cursor[i] = 0;
    if (t < 128) { below[t] = 0; candCnt[t] = 0; }
    if (t == 0) { ovCnt[0] = 0; ovCnt[1] = 0; ovCnt[2] = 0; }
}

// ---------------- GEMM: xw = x @ W^T (split-bf16 MFMA, fp16 out) ----------
__global__ __launch_bounds__(256) void k_gemm(
        const float* __restrict__ x, const short* __restrict__ Whi,
        const short* __restrict__ Wlo, _Float16* __restrict__ xw, int n) {
    __shared__ float trn[4 * 16 * 132];            // 33.8 KB
    const int t = threadIdx.x;
    const int lane = t & 63, wv = t >> 6;
    const int quad = lane >> 4, m = lane & 15;
    const int rowBase = blockIdx.x * 64 + wv * 16;
    const int r = rowBase + m;
    const int rl = r < n ? r : (n - 1);
    f32x4 acc[8];
    #pragma unroll
    for (int q = 0; q < 8; q++) acc[q] = (f32x4){0.f, 0.f, 0.f, 0.f};
    #pragma unroll
    for (int s = 0; s < 4; s++) {
        const float* xp = x + (size_t)rl * 128 + s * 32 + quad * 8;
        float4 p0 = *(const float4*)xp;
        float4 p1 = *(const float4*)(xp + 4);
        float f[8] = {p0.x, p0.y, p0.z, p0.w, p1.x, p1.y, p1.z, p1.w};
        short8 ah, al;
        #pragma unroll
        for (int j = 0; j < 8; j++) {
            unsigned short hb = f2bf(f[j]);
            float hf = __uint_as_float((unsigned)hb << 16);
            ah[j] = (short)hb;
            al[j] = (short)f2bf(f[j] - hf);
        }
        #pragma unroll
        for (int q = 0; q < 8; q++) {
            short8 bh = *(const short8*)(Whi + (((s * 8 + q) * 64 + lane) << 3));
            short8 bl = *(const short8*)(Wlo + (((s * 8 + q) * 64 + lane) << 3));
            acc[q] = __builtin_amdgcn_mfma_f32_16x16x32_bf16(ah, bh, acc[q], 0, 0, 0);
            acc[q] = __builtin_amdgcn_mfma_f32_16x16x32_bf16(al, bh, acc[q], 0, 0, 0);
            acc[q] = __builtin_amdgcn_mfma_f32_16x16x32_bf16(ah, bl, acc[q], 0, 0, 0);
        }
    }
    float* tw = trn + wv * (16 * 132);
    #pragma unroll
    for (int q = 0; q < 8; q++)
        #pragma unroll
        for (int e = 0; e < 4; e++)
            tw[(quad * 4 + e) * 132 + q * 16 + m] = acc[q][e];
    // wave-private ds_write->ds_read ordered by lgkmcnt: no barrier
    #pragma unroll
    for (int i = 0; i < 4; i++) {
        int row = i * 4 + (lane >> 4);
        int c8 = lane & 15;
        const float* tp = tw + row * 132 + c8 * 8;
        float4 p0 = *(const float4*)tp;
        float4 p1 = *(const float4*)(tp + 4);
        half8 o;
        o[0] = (_Float16)p0.x; o[1] = (_Float16)p0.y;
        o[2] = (_Float16)p0.z; o[3] = (_Float16)p0.w;
        o[4] = (_Float16)p1.x; o[5] = (_Float16)p1.y;
        o[6] = (_Float16)p1.z; o[7] = (_Float16)p1.w;
        int grow = rowBase + row;
        if (grow < n) *(half8*)(xw + (size_t)grow * 128 + c8 * 8) = o;
    }
}

// ---------------- BIN: chunked LDS binning of edges by dst bucket ---------
__global__ __launch_bounds__(256) void k_bin(
        const int* __restrict__ src, const int* __restrict__ dst, int E,
        int* __restrict__ cursor, int2* __restrict__ binned,
        int* __restrict__ ovCnt, int2* __restrict__ ovBuf, int nbk) {
    __shared__ char smem[39168];
    const int t = threadIdx.x;
    int2* stage = (int2*)smem;                 // 32 KB
    int* hist  = (int*)(smem + 32768);
    int* gbase = hist + NBKMAX;
    int* hist2 = gbase + NBKMAX;
    int* sbase = hist2 + NBKMAX;
    const int e0 = (int)blockIdx.x * CH;
    const int len = min(CH, E - e0);
    for (int i = t; i < nbk; i += 256) { hist[i] = 0; hist2[i] = 0; }
    __syncthreads();
    for (int k = t; k < len; k += 256) {
        int s = src[e0 + k], d = dst[e0 + k];
        stage[k] = make_int2(s, d);
        atomicAdd(&hist[d >> 8], 1);
    }
    __syncthreads();
    for (int i = t; i < nbk; i += 256) {
        int c = hist[i];
        if (c) {
            int g = atomicAdd(&cursor[i], c);
            if (g + c <= BCAP) gbase[i] = g;
            else {                              // p ~ 1e-13: spill chunk
                gbase[i] = -1;
                sbase[i] = atomicAdd(ovCnt, c);
            }
        }
    }
    __syncthreads();
    for (int k = t; k < len; k += 256) {
        int2 e = stage[k];
        int b = e.y >> 8;
        int p = atomicAdd(&hist2[b], 1);
        int g = gbase[b];
        if (g >= 0) binned[(size_t)b * BCAP + g + p] = e;
        else {
            int o = sbase[b] + p;
            if (o < OVCAP) ovBuf[o] = make_int2(e.y, e.x);
        }
    }
}

// ---------------- build: single-pass LDS adjacency + coalesced dump -------
__global__ __launch_bounds__(512) void k_build(int2* __restrict__ binned,
                                               const int* __restrict__ cursor,
                                               float* __restrict__ dinv,
                                               unsigned char* __restrict__ deg8,
                                               int* __restrict__ ovCnt,
                                               int2* __restrict__ ovBuf,
                                               int* __restrict__ spillNodes, int n) {
    __shared__ int ladj[256 * DSTR];               // 32 KB
    __shared__ int lcnt[256];
    const int b = blockIdx.x, t = threadIdx.x;
    const int cnt = min(cursor[b], BCAP);
    const size_t e0 = (size_t)b * BCAP;
    if (t < 256) lcnt[t] = 0;
    __syncthreads();
    for (int k = t; k < cnt; k += 512) {
        int2 e = binned[e0 + k];                   // (src, dst)
        int li = e.y & 255;
        int pos = atomicAdd(&lcnt[li], 1);
        if (pos < DSTR) ladj[li * DSTR + pos] = e.x;
        else {
            int o = atomicAdd(ovCnt, 1);
            if (o < OVCAP) ovBuf[o] = make_int2(e.y, e.x);
        }
    }
    __syncthreads();
    int4* adjOut = (int4*)((int*)binned + e0 * 2);
    const int4* lsrc4 = (const int4*)ladj;
    for (int i = t; i < 2048; i += 512) adjOut[i] = lsrc4[i];
    if (t < 256) {
        int node = b * 256 + t;
        if (node < n) {
            int deg = lcnt[t];
            dinv[node] = (float)(1.0 / sqrt((double)(deg + 1)));
            deg8[node] = (unsigned char)(deg < 255 ? deg : 255);   // true degree
            if (deg > DSTR) {
                int p = atomicAdd(ovCnt + 1, 1);                   // spillCnt
                if (p < SPCAP) spillNodes[p] = node;
            }
        }
    }
}

// ---------------- main aggregation: 1 node/wave, pure gather, fp16 h ------
// Half-range launch (diagnostic split): d in [n0, n1).
__global__ __launch_bounds__(256) void k_aggH(const _Float16* __restrict__ xw,
                                              const unsigned char* __restrict__ deg8,
                                              const int* __restrict__ adjAll,
                                              const float* __restrict__ dinv,
                                              const float* __restrict__ conv_b,
                                              _Float16* __restrict__ h,
                                              int n0, int n1) {
    const int d = n0 + blockIdx.x * 4 + (threadIdx.x >> 6);
    if (d >= n1) return;
    const int lane = threadIdx.x & 63;
    const int l32 = lane & 31;
    int degT = deg8[d];
    const int degB = degT < DSTR ? degT : DSTR;    // spill rows fixed later
    const float dd = dinv[d];
    const int* adjRow = adjAll + (size_t)(d >> 8) * (BCAP * 2) + (d & 255) * DSTR;
    int aj = adjRow[l32];
    bool ev = (lane < 32) && (l32 < degB);
    int ajs = ev ? aj : 0;
    float dv = ev ? dinv[ajs] : 0.f;
    const half2v* xwv = (const half2v*)xw;
    half2v a = xwv[(size_t)d * 64 + lane];
    float ax = dd * dd * (float)a.x, ay = dd * dd * (float)a.y;   // self-loop
    int j = 0;
    for (; j + 8 <= degB; j += 8) {
        int s[8];
        float w[8];
        #pragma unroll
        for (int q = 0; q < 8; q++) {
            s[q] = __shfl(ajs, j + q, 64);
            w[q] = dd * __shfl(dv, j + q, 64);
        }
        #pragma unroll
        for (int q = 0; q < 8; q++) {
            half2v v = xwv[(size_t)s[q] * 64 + lane];
            ax += w[q] * (float)v.x;
            ay += w[q] * (float)v.y;
        }
    }
    if (j < degB) {
        int s[8];
        float w[8];
        #pragma unroll
        for (int q = 0; q < 8; q++) {
            int idx = j + q;
            bool ok = idx < degB;
            int lsrc = ok ? idx : 0;
            int sv = __shfl(ajs, lsrc, 64);
            float wv = dd * __shfl(dv, lsrc, 64);
            s[q] = ok ? sv : 0;
            w[q] = ok ? wv : 0.f;
        }
        #pragma unroll
        for (int q = 0; q < 8; q++) {
            half2v v = xwv[(size_t)s[q] * 64 + lane];
            ax += w[q] * (float)v.x;
            ay += w[q] * (float)v.y;
        }
    }
    float2 cb = ((const float2*)conv_b)[lane];
    half2v o;
    o.x = (_Float16)(ax + cb.x);
    o.y = (_Float16)(ay + cb.y);
    ((half2v*)h)[(size_t)d * 64 + lane] = o;
}

// ---------------- fused: sampled bracket (blocks 0-127) || spill fix ------
// Sample tolerates <=1 stale sampled row (expected 0.5/3125; 8-sigma bracket
// margin). Classify reads post-fix h, so below/cand stay exact.
__global__ __launch_bounds__(256) void k_sampleSpill(
        _Float16* h, int n,
        unsigned* __restrict__ Lkey, unsigned* __restrict__ Ukey,
        const _Float16* __restrict__ xw, const int* __restrict__ spillNodes,
        const int* __restrict__ adjAll, const float* __restrict__ dinv,
        const float* __restrict__ conv_b, const int2* __restrict__ ovBuf,
        const int* __restrict__ ovCnt) {
    const int t = threadIdx.x;
    if (blockIdx.x >= 128) {
        // ---- spill-fix role (16 blocks, threads 0-127) ----
        int m = ovCnt[0];  if (m > OVCAP) m = OVCAP;
        int sp = ovCnt[1]; if (sp > SPCAP) sp = SPCAP;
        if (t >= 128) return;
        for (int i = (int)blockIdx.x - 128; i < sp; i += 16) {
            const int d = spillNodes[i];
            const float dd = dinv[d];
            float acc = dd * dd * (float)xw[(size_t)d * 128 + t];
            const int* adjRow = adjAll + (size_t)(d >> 8) * (BCAP * 2) + (d & 255) * DSTR;
            for (int j = 0; j < DSTR; j++) {
                int a = adjRow[j];
                acc += dd * dinv[a] * (float)xw[(size_t)a * 128 + t];
            }
            for (int k = 0; k < m; k++) {
                int2 e = ovBuf[k];                 // (dst, src)
                if (e.x == d)
                    acc += dd * dinv[e.y] * (float)xw[(size_t)e.y * 128 + t];
            }
            h[(size_t)d * 128 + t] = (_Float16)(acc + conv_b[t]);
        }
        return;
    }
    // ---- sample role (128 blocks, one column each) ----
    __shared__ int hist[2048];
    __shared__ int wsum[4];
    const int c = blockIdx.x;
    for (int i = t; i < 2048; i += 256) hist[i] = 0;
    __syncthreads();
    const int ns = (n + 31) >> 5;
    for (int i = t; i < ns; i += 256) {
        float v = (float)h[(size_t)(i << 5) * 128 + c];
        atomicAdd(&hist[ordKey(v) >> 21], 1);
    }
    __syncthreads();
    int ps = 0;
    #pragma unroll
    for (int b = 0; b < 8; b++) ps += hist[t * 8 + b];
    const int lane = t & 63, wv = t >> 6;
    int sc = ps;
    #pragma unroll
    for (int off = 1; off < 64; off <<= 1) {
        int y = __shfl_up(sc, off, 64);
        if (lane >= off) sc += y;
    }
    if (lane == 63) wsum[wv] = sc;
    __syncthreads();
    int wbase = 0;
    for (int ww = 0; ww < wv; ww++) wbase += wsum[ww];
    const int excl = wbase + sc - ps;
    const int sMid = (ns - 1) >> 1;
    const int delta = (int)(4.0f * sqrtf((float)ns)) + 1;
    int sLo = sMid - delta; if (sLo < 0) sLo = 0;
    int sHi = sMid + delta; if (sHi > ns - 1) sHi = ns - 1;
    if (sLo >= excl && sLo < excl + ps) {
        int rem = sLo - excl, b = t * 8;
        for (;; b++) { int cc = hist[b]; if (rem < cc) break; rem -= cc; }
        Lkey[c] = (unsigned)b << 21;
    }
    if (sHi >= excl && sHi < excl + ps) {
        int rem = sHi - excl, b = t * 8;
        for (;; b++) { int cc = hist[b]; if (rem < cc) break; rem -= cc; }
        Ukey[c] = (((unsigned)(b + 1)) << 21) - 1u;
    }
}

// ---------------- classify: stream fp16 h, below-count + fp16 candidates --
// 512 blocks: 12 iters/thread; flush chains 512 deep. jb invariant:
// stride*8 = 512*256*8 multiple of 128.
__global__ __launch_bounds__(256) void k_classify(const _Float16* __restrict__ h,
                                                  int total8,
                                                  const unsigned* __restrict__ Lkey,
                                                  const unsigned* __restrict__ Ukey,
                                                  int* __restrict__ below,
                                                  int* __restrict__ candCnt,
                                                  _Float16* __restrict__ cand) {
    __shared__ _Float16 buf[128 * CSTR];  // 24.25 KB, stride 97 (bank-spread)
    __shared__ int cN[128], cB[128];
    const int t = threadIdx.x;
    for (int i = t; i < 128; i += 256) { cN[i] = 0; cB[i] = 0; }
    __syncthreads();
    const int stride = gridDim.x * blockDim.x;
    const int i0 = blockIdx.x * blockDim.x + t;
    const int jb = (i0 << 3) & 127;     // stride*8 % 128 == 0 -> invariant
    unsigned L[8], U[8];
    #pragma unroll
    for (int k = 0; k < 8; k++) { L[k] = Lkey[jb + k]; U[k] = Ukey[jb + k]; }
    int b[8] = {0, 0, 0, 0, 0, 0, 0, 0};
    const half8* hv = (const half8*)h;
    for (int i = i0; i < total8; i += stride) {
        half8 v = hv[i];
        #pragma unroll
        for (int k = 0; k < 8; k++) {
            float f = (float)v[k];
            unsigned u = ordKey(f);
            if (u < L[k]) b[k]++;
            else if (u <= U[k]) {
                int p = atomicAdd(&cN[jb + k], 1);
                if (p < CCAP) buf[(jb + k) * CSTR + p] = v[k];
                else {
                    int g = atomicAdd(&candCnt[jb + k], 1);
                    if (g < CAP) cand[(size_t)(jb + k) * CAP + g] = v[k];
                }
            }
        }
    }
    #pragma unroll
    for (int k = 0; k < 8; k++)
        if (b[k]) atomicAdd(&cB[jb + k], b[k]);
    __syncthreads();
    if (t < 128) {
        if (cB[t]) atomicAdd(&below[t], cB[t]);
        int nn = cN[t] < CCAP ? cN[t] : CCAP;
        if (nn) {
            int base = atomicAdd(&candCnt[t], nn);
            for (int k2 = 0; k2 < nn && base + k2 < CAP; k2++)
                cand[(size_t)t * CAP + base + k2] = buf[t * CSTR + k2];
        }
    }
}

// ---------------- final: register-resident binary-search select + MLP -----
// 1024 threads, MPT=24: key array truly fits in VGPRs (v16 spilled at
// MPT=96). 16 MSB-first iterations of count(<pivot): unrolled compares +
// wave shfl reduce + 16-entry LDS sum. Greedy bit-build over the prefix
// feasible set = exact r-th order statistic.
__global__ __launch_bounds__(1024) void k_finalMlp(
        const _Float16* __restrict__ cand, const int* __restrict__ candCnt,
        const int* __restrict__ below, int n, float* __restrict__ med,
        int* __restrict__ doneCnt,
        const float* __restrict__ w1, const float* __restrict__ b1,
        const float* __restrict__ w2, const float* __restrict__ b2,
        const float* __restrict__ w3, const float* __restrict__ b3,
        float* __restrict__ out) {
    __shared__ int wsum[16];
    __shared__ int lastFlag;
    const int c = blockIdx.x, t = threadIdx.x;
    const int lane = t & 63, wv = t >> 6;
    int cnt = candCnt[c]; if (cnt > CAP) cnt = CAP;
    const unsigned short* cp = (const unsigned short*)cand + (size_t)c * CAP;
    int r = (n - 1) / 2 - below[c];
    if (r < 0) r = 0;
    if (r >= cnt) r = cnt - 1;
    // load phase: independent unrolled coalesced loads -> registers
    unsigned short myk[MPT];
    #pragma unroll
    for (int mi = 0; mi < MPT; mi++) {
        int i = t + mi * 1024;
        unsigned ub = (i < cnt) ? (unsigned)cp[i] : 0u;
        unsigned k = (ub & 0x8000u) ? (~ub & 0xFFFFu) : (ub | 0x8000u);
        myk[mi] = (i < cnt) ? (unsigned short)k : (unsigned short)0xFFFFu;
    }
    // 16-iteration binary search on the 16-bit ordered-key space
    unsigned cur = 0;
    for (int bit = 15; bit >= 0; bit--) {
        const unsigned pivot = cur | (1u << bit);
        int lc = 0;
        #pragma unroll
        for (int mi = 0; mi < MPT; mi++) lc += ((unsigned)myk[mi] < pivot) ? 1 : 0;
        #pragma unroll
        for (int off = 32; off > 0; off >>= 1) lc += __shfl_down(lc, off, 64);
        if (lane == 0) wsum[wv] = lc;
        __syncthreads();
        int tot = 0;
        #pragma unroll
        for (int ww = 0; ww < 16; ww++) tot += wsum[ww];
        if (tot <= r) cur = pivot;                 // uniform across block
        __syncthreads();
    }
    if (t == 0) {
        unsigned short bits = (cur & 0x8000u) ? (unsigned short)(cur & 0x7FFFu)
                                              : (unsigned short)(~cur & 0xFFFFu);
        _Float16 hv;
        *(unsigned short*)&hv = bits;
        med[c] = (float)hv;
        __threadfence();
        int old = atomicAdd(doneCnt, 1);
        lastFlag = (old == 127);
    }
    __syncthreads();
    if (!lastFlag) return;
    __threadfence();                                // acquire all med writes
    // ---- MLP role (one block) ----
    __shared__ float m[128], a1[64], a2[64];
    if (t < 128) m[t] = med[t];
    __syncthreads();
    if (t < 64) {
        float acc = b1[t];
        for (int f = 0; f < 128; f++) acc += m[f] * w1[t * 128 + f];
        a1[t] = tanhf(acc);
    }
    __syncthreads();
    if (t < 64) {
        float acc = b2[t];
        for (int f = 0; f < 64; f++) acc += a1[f] * w2[t * 64 + f];
        a2[t] = tanhf(acc);
    }
    __syncthreads();
    if (t == 0) {
        float acc = b3[0];
        for (int f = 0; f < 64; f++) acc += a2[f] * w3[f];
        out[0] = acc;
    }
}

extern "C" void kernel_launch(void* const* d_in, const int* in_sizes, int n_in,
                              void* d_out, int out_size, void* d_ws, size_t ws_size,
                              hipStream_t stream) {
    const float* x      = (const float*)d_in[0];
    const int*   ei     = (const int*)d_in[1];
    const float* conv_W = (const float*)d_in[2];
    const float* conv_b = (const float*)d_in[3];
    const float* w1 = (const float*)d_in[4];
    const float* b1 = (const float*)d_in[5];
    const float* w2 = (const float*)d_in[6];
    const float* b2 = (const float*)d_in[7];
    const float* w3 = (const float*)d_in[8];
    const float* b3 = (const float*)d_in[9];

    const int N = in_sizes[0] / 128;
    const int E = in_sizes[1] / 2;
    const int* src = ei;
    const int* dst = ei + E;
    const int NBK = (N + 255) / 256;

    char* p = (char*)d_ws;
    auto alloc = [&](size_t bytes) -> char* {
        char* q = p;
        p += (bytes + 255) & ~(size_t)255;
        return q;
    };
    _Float16* xw  = (_Float16*)alloc((size_t)N * 128 * 2);  // fp16
    _Float16* h   = (_Float16*)alloc((size_t)N * 128 * 2);  // fp16
    int2*  binned = (int2*)alloc((size_t)NBK * BCAP * 8);   // 14.4 MB; becomes adj
    _Float16* cand = (_Float16*)alloc((size_t)128 * CAP * 2);  // 6.3 MB fp16
    float* dinv   = (float*)alloc((size_t)N * 4);
    unsigned char* deg8 = (unsigned char*)alloc((size_t)N);
    int*   cursor = (int*)alloc((size_t)NBK * 4);
    short* Whi    = (short*)alloc(16384 * 2);
    short* Wlo    = (short*)alloc(16384 * 2);
    int2*  ovBuf  = (int2*)alloc((size_t)OVCAP * 8);
    int*   ovCnt  = (int*)alloc(256);             // [0]=ov, [1]=spill, [2]=done
    int*   spillNodes = (int*)alloc((size_t)SPCAP * 4);
    unsigned* Lkey = (unsigned*)alloc(128 * 4);
    unsigned* Ukey = (unsigned*)alloc(128 * 4);
    int*   below   = (int*)alloc(128 * 4);
    int*   candCnt = (int*)alloc(128 * 4);
    float* med     = (float*)alloc(128 * 4);

    const int GB   = (N + 63) / 64;          // gemm blocks
    const int BINB = (E + CH - 1) / CH;      // bin blocks
    const int NH   = ((N / 2) + 3) & ~3;     // agg half split (mult of 4)

    k_init<<<2, 256, 0, stream>>>(cursor, below, candCnt, ovCnt, conv_W, Whi, Wlo, NBK);
    k_gemm<<<GB, 256, 0, stream>>>(x, Whi, Wlo, xw, N);
    k_bin<<<BINB, 256, 0, stream>>>(src, dst, E, cursor, binned, ovCnt, ovBuf, NBK);
    k_build<<<NBK, 512, 0, stream>>>(binned, cursor, dinv, deg8, ovCnt, ovBuf,
                                     spillNodes, N);
    k_aggH<<<(NH + 3) / 4, 256, 0, stream>>>(xw, deg8, (const int*)binned, dinv,
                                             conv_b, h, 0, NH);
    k_aggH<<<(N - NH + 3) / 4, 256, 0, stream>>>(xw, deg8, (const int*)binned, dinv,
                                                 conv_b, h, NH, N);
    k_sampleSpill<<<144, 256, 0, stream>>>(h, N, Lkey, Ukey, xw, spillNodes,
                                           (const int*)binned, dinv, conv_b,
                                           ovBuf, ovCnt);
    k_classify<<<512, 256, 0, stream>>>(h, N * 16, Lkey, Ukey, below, candCnt, cand);
    k_finalMlp<<<128, 1024, 0, stream>>>(cand, candCnt, below, N, med, ovCnt + 2,
                                         w1, b1, w2, b2, w3, b3, (float*)d_out);
}

// Round 10
// 275.988 us; speedup vs baseline: 1.1259x; 1.0865x over previous
//
#include <hip/hip_runtime.h>
#include <math.h>

// GraphCritic: GCNConv (sym-norm + self-loops) -> per-column lower median ->
// tanh MLP -> scalar.
// v18: atomic-chain sharding + re-fusion. Budget analysis: all kernels now
//      <=40us (top-5 = harness fill at 41), but ~160us of the 300 is in the
//      hidden 31-40us mid-tier. The proven failure mode here is same-address
//      atomic chains ~ block count (v10/v13/v15): k_classify still runs
//      512-deep chains on below[c]/candCnt[c]. Fix: shard 8 ways by
//      blockIdx&7 (below8/candCnt8; cand split into 8 regions x 3072/col,
//      +32 sigma). finalMlp sums shards, loads 8 regions x 3 slots (MPT=24
//      unchanged, no spill). Also: gemm+bin re-fused (concurrent roles,
//      proven v8-v13; split was diagnostic), build at 1024 threads (chain
//      halves), aggH unsplit. 9 -> 7 dispatches.

#define CAP    24576   // candidate capacity per column
#define NREG   8       // candCnt/below shards (by blockIdx&7)
#define RCAP   3072    // per-region candidate capacity (CAP/NREG, +32 sigma)
#define MPT    24      // keys per thread in k_finalMlp (8 regions x 3)
#define CCAP   96      // per-block per-column LDS candidate slots
#define CSTR   97      // buf column stride in halfs (bank-spread padding)
#define DSTR   32      // adjacency slots per node
#define OVCAP  4096    // overflow edge capacity (deg>32 spill, expect ~60)
#define SPCAP  2048    // spill node list capacity (expect ~15)
#define BCAP   4608    // edges per 256-node bucket (mean 4092, sd 64: +8 sigma)
#define NBKMAX 400
#define CH     4096    // bin chunk size

typedef __attribute__((ext_vector_type(8))) short short8;   // 8 bf16
typedef __attribute__((ext_vector_type(4))) float f32x4;
typedef __attribute__((ext_vector_type(8))) _Float16 half8;
typedef __attribute__((ext_vector_type(2))) _Float16 half2v;

__device__ __forceinline__ unsigned ordKey(float x) {
    unsigned u = __float_as_uint(x);
    return (u & 0x80000000u) ? ~u : (u | 0x80000000u);
}
__device__ __forceinline__ unsigned short f2bf(float f) {   // RNE
    unsigned u = __float_as_uint(f);
    return (unsigned short)((u + 0x7FFFu + ((u >> 16) & 1u)) >> 16);
}

// ---------------- init: zero counters; W -> frag layout --------------------
__global__ void k_init(int* __restrict__ cursor, int* __restrict__ below8,
                       int* __restrict__ candCnt8, int* __restrict__ ovCnt,
                       const float* __restrict__ W, short* __restrict__ Whi,
                       short* __restrict__ Wlo, int nbk) {
    if (blockIdx.x == 1) {
        for (int idx = threadIdx.x; idx < 16384; idx += 256) {
            int j = idx & 7, lane = (idx >> 3) & 63;
            int t = (idx >> 9) & 7, s = idx >> 12;
            int row = t * 16 + (lane & 15);
            int k = s * 32 + (lane >> 4) * 8 + j;
            float w = W[row * 128 + k];
            unsigned short hb = f2bf(w);
            float hf = __uint_as_float((unsigned)hb << 16);
            Whi[idx] = (short)hb;
            Wlo[idx] = (short)f2bf(w - hf);
        }
        return;
    }
    int t = threadIdx.x;
    for (int i = t; i < nbk; i += 256) cursor[i] = 0;
    for (int i = t; i < NREG * 128; i += 256) { below8[i] = 0; candCnt8[i] = 0; }
    if (t == 0) { ovCnt[0] = 0; ovCnt[1] = 0; ovCnt[2] = 0; }
}

// ---------------- fused: split-bf16 MFMA GEMM + bucket binning -------------
// Blocks [0,GB): xw = x @ W^T (fp16 out). Blocks [GB,GB+BINB): chunked LDS
// binning. LDS union: gemm 33.8KB transpose slab; bin 32KB stage + hists.
__global__ __launch_bounds__(256) void k_binGemm(
        const float* __restrict__ x, const short* __restrict__ Whi,
        const short* __restrict__ Wlo, _Float16* __restrict__ xw, int n, int GB,
        const int* __restrict__ src, const int* __restrict__ dst, int E,
        int* __restrict__ cursor, int2* __restrict__ binned,
        int* __restrict__ ovCnt, int2* __restrict__ ovBuf, int nbk) {
    __shared__ char smem[39168];
    const int t = threadIdx.x;
    if ((int)blockIdx.x < GB) {
        // ---- GEMM role ----
        float* trn = (float*)smem;                 // 4 waves x 16 x 132 floats
        const int lane = t & 63, wv = t >> 6;
        const int quad = lane >> 4, m = lane & 15;
        const int rowBase = blockIdx.x * 64 + wv * 16;
        const int r = rowBase + m;
        const int rl = r < n ? r : (n - 1);
        f32x4 acc[8];
        #pragma unroll
        for (int q = 0; q < 8; q++) acc[q] = (f32x4){0.f, 0.f, 0.f, 0.f};
        #pragma unroll
        for (int s = 0; s < 4; s++) {
            const float* xp = x + (size_t)rl * 128 + s * 32 + quad * 8;
            float4 p0 = *(const float4*)xp;
            float4 p1 = *(const float4*)(xp + 4);
            float f[8] = {p0.x, p0.y, p0.z, p0.w, p1.x, p1.y, p1.z, p1.w};
            short8 ah, al;
            #pragma unroll
            for (int j = 0; j < 8; j++) {
                unsigned short hb = f2bf(f[j]);
                float hf = __uint_as_float((unsigned)hb << 16);
                ah[j] = (short)hb;
                al[j] = (short)f2bf(f[j] - hf);
            }
            #pragma unroll
            for (int q = 0; q < 8; q++) {
                short8 bh = *(const short8*)(Whi + (((s * 8 + q) * 64 + lane) << 3));
                short8 bl = *(const short8*)(Wlo + (((s * 8 + q) * 64 + lane) << 3));
                acc[q] = __builtin_amdgcn_mfma_f32_16x16x32_bf16(ah, bh, acc[q], 0, 0, 0);
                acc[q] = __builtin_amdgcn_mfma_f32_16x16x32_bf16(al, bh, acc[q], 0, 0, 0);
                acc[q] = __builtin_amdgcn_mfma_f32_16x16x32_bf16(ah, bl, acc[q], 0, 0, 0);
            }
        }
        float* tw = trn + wv * (16 * 132);
        #pragma unroll
        for (int q = 0; q < 8; q++)
            #pragma unroll
            for (int e = 0; e < 4; e++)
                tw[(quad * 4 + e) * 132 + q * 16 + m] = acc[q][e];
        // wave-private ds_write->ds_read ordered by lgkmcnt: no barrier
        #pragma unroll
        for (int i = 0; i < 4; i++) {
            int row = i * 4 + (lane >> 4);
            int c8 = lane & 15;
            const float* tp = tw + row * 132 + c8 * 8;
            float4 p0 = *(const float4*)tp;
            float4 p1 = *(const float4*)(tp + 4);
            half8 o;
            o[0] = (_Float16)p0.x; o[1] = (_Float16)p0.y;
            o[2] = (_Float16)p0.z; o[3] = (_Float16)p0.w;
            o[4] = (_Float16)p1.x; o[5] = (_Float16)p1.y;
            o[6] = (_Float16)p1.z; o[7] = (_Float16)p1.w;
            int grow = rowBase + row;
            if (grow < n) *(half8*)(xw + (size_t)grow * 128 + c8 * 8) = o;
        }
    } else {
        // ---- BIN role ----
        int2* stage = (int2*)smem;                 // 32 KB
        int* hist  = (int*)(smem + 32768);
        int* gbase = hist + NBKMAX;
        int* hist2 = gbase + NBKMAX;
        int* sbase = hist2 + NBKMAX;
        const int e0 = ((int)blockIdx.x - GB) * CH;
        const int len = min(CH, E - e0);
        for (int i = t; i < nbk; i += 256) { hist[i] = 0; hist2[i] = 0; }
        __syncthreads();
        for (int k = t; k < len; k += 256) {
            int s = src[e0 + k], d = dst[e0 + k];
            stage[k] = make_int2(s, d);
            atomicAdd(&hist[d >> 8], 1);
        }
        __syncthreads();
        for (int i = t; i < nbk; i += 256) {
            int c = hist[i];
            if (c) {
                int g = atomicAdd(&cursor[i], c);
                if (g + c <= BCAP) gbase[i] = g;
                else {                              // p ~ 1e-13: spill chunk
                    gbase[i] = -1;
                    sbase[i] = atomicAdd(ovCnt, c);
                }
            }
        }
        __syncthreads();
        for (int k = t; k < len; k += 256) {
            int2 e = stage[k];
            int b = e.y >> 8;
            int p = atomicAdd(&hist2[b], 1);
            int g = gbase[b];
            if (g >= 0) binned[(size_t)b * BCAP + g + p] = e;
            else {
                int o = sbase[b] + p;
                if (o < OVCAP) ovBuf[o] = make_int2(e.y, e.x);
            }
        }
    }
}

// ---------------- build: single-pass LDS adjacency + coalesced dump -------
// 1024 threads (v18): 391 blocks are 1.5/CU; quarter the per-block chain.
__global__ __launch_bounds__(1024) void k_build(int2* __restrict__ binned,
                                                const int* __restrict__ cursor,
                                                float* __restrict__ dinv,
                                                unsigned char* __restrict__ deg8,
                                                int* __restrict__ ovCnt,
                                                int2* __restrict__ ovBuf,
                                                int* __restrict__ spillNodes, int n) {
    __shared__ int ladj[256 * DSTR];               // 32 KB
    __shared__ int lcnt[256];
    const int b = blockIdx.x, t = threadIdx.x;
    const int cnt = min(cursor[b], BCAP);
    const size_t e0 = (size_t)b * BCAP;
    if (t < 256) lcnt[t] = 0;
    __syncthreads();
    for (int k = t; k < cnt; k += 1024) {
        int2 e = binned[e0 + k];                   // (src, dst)
        int li = e.y & 255;
        int pos = atomicAdd(&lcnt[li], 1);
        if (pos < DSTR) ladj[li * DSTR + pos] = e.x;
        else {
            int o = atomicAdd(ovCnt, 1);
            if (o < OVCAP) ovBuf[o] = make_int2(e.y, e.x);
        }
    }
    __syncthreads();
    int4* adjOut = (int4*)((int*)binned + e0 * 2);
    const int4* lsrc4 = (const int4*)ladj;
    for (int i = t; i < 2048; i += 1024) adjOut[i] = lsrc4[i];
    if (t < 256) {
        int node = b * 256 + t;
        if (node < n) {
            int deg = lcnt[t];
            dinv[node] = (float)(1.0 / sqrt((double)(deg + 1)));
            deg8[node] = (unsigned char)(deg < 255 ? deg : 255);   // true degree
            if (deg > DSTR) {
                int p = atomicAdd(ovCnt + 1, 1);                   // spillCnt
                if (p < SPCAP) spillNodes[p] = node;
            }
        }
    }
}

// ---------------- main aggregation: 1 node/wave, pure gather, fp16 h ------
__global__ __launch_bounds__(256) void k_aggH(const _Float16* __restrict__ xw,
                                              const unsigned char* __restrict__ deg8,
                                              const int* __restrict__ adjAll,
                                              const float* __restrict__ dinv,
                                              const float* __restrict__ conv_b,
                                              _Float16* __restrict__ h, int n) {
    const int d = blockIdx.x * 4 + (threadIdx.x >> 6);
    if (d >= n) return;
    const int lane = threadIdx.x & 63;
    const int l32 = lane & 31;
    int degT = deg8[d];
    const int degB = degT < DSTR ? degT : DSTR;    // spill rows fixed later
    const float dd = dinv[d];
    const int* adjRow = adjAll + (size_t)(d >> 8) * (BCAP * 2) + (d & 255) * DSTR;
    int aj = adjRow[l32];
    bool ev = (lane < 32) && (l32 < degB);
    int ajs = ev ? aj : 0;
    float dv = ev ? dinv[ajs] : 0.f;
    const half2v* xwv = (const half2v*)xw;
    half2v a = xwv[(size_t)d * 64 + lane];
    float ax = dd * dd * (float)a.x, ay = dd * dd * (float)a.y;   // self-loop
    int j = 0;
    for (; j + 8 <= degB; j += 8) {
        int s[8];
        float w[8];
        #pragma unroll
        for (int q = 0; q < 8; q++) {
            s[q] = __shfl(ajs, j + q, 64);
            w[q] = dd * __shfl(dv, j + q, 64);
        }
        #pragma unroll
        for (int q = 0; q < 8; q++) {
            half2v v = xwv[(size_t)s[q] * 64 + lane];
            ax += w[q] * (float)v.x;
            ay += w[q] * (float)v.y;
        }
    }
    if (j < degB) {
        int s[8];
        float w[8];
        #pragma unroll
        for (int q = 0; q < 8; q++) {
            int idx = j + q;
            bool ok = idx < degB;
            int lsrc = ok ? idx : 0;
            int sv = __shfl(ajs, lsrc, 64);
            float wv = dd * __shfl(dv, lsrc, 64);
            s[q] = ok ? sv : 0;
            w[q] = ok ? wv : 0.f;
        }
        #pragma unroll
        for (int q = 0; q < 8; q++) {
            half2v v = xwv[(size_t)s[q] * 64 + lane];
            ax += w[q] * (float)v.x;
            ay += w[q] * (float)v.y;
        }
    }
    float2 cb = ((const float2*)conv_b)[lane];
    half2v o;
    o.x = (_Float16)(ax + cb.x);
    o.y = (_Float16)(ay + cb.y);
    ((half2v*)h)[(size_t)d * 64 + lane] = o;
}

// ---------------- fused: sampled bracket (blocks 0-127) || spill fix ------
// Sample tolerates <=1 stale sampled row (expected 0.5/3125; 8-sigma bracket
// margin). Classify reads post-fix h, so below/cand stay exact.
__global__ __launch_bounds__(256) void k_sampleSpill(
        _Float16* h, int n,
        unsigned* __restrict__ Lkey, unsigned* __restrict__ Ukey,
        const _Float16* __restrict__ xw, const int* __restrict__ spillNodes,
        const int* __restrict__ adjAll, const float* __restrict__ dinv,
        const float* __restrict__ conv_b, const int2* __restrict__ ovBuf,
        const int* __restrict__ ovCnt) {
    const int t = threadIdx.x;
    if (blockIdx.x >= 128) {
        // ---- spill-fix role (16 blocks, threads 0-127) ----
        int m = ovCnt[0];  if (m > OVCAP) m = OVCAP;
        int sp = ovCnt[1]; if (sp > SPCAP) sp = SPCAP;
        if (t >= 128) return;
        for (int i = (int)blockIdx.x - 128; i < sp; i += 16) {
            const int d = spillNodes[i];
            const float dd = dinv[d];
            float acc = dd * dd * (float)xw[(size_t)d * 128 + t];
            const int* adjRow = adjAll + (size_t)(d >> 8) * (BCAP * 2) + (d & 255) * DSTR;
            for (int j = 0; j < DSTR; j++) {
                int a = adjRow[j];
                acc += dd * dinv[a] * (float)xw[(size_t)a * 128 + t];
            }
            for (int k = 0; k < m; k++) {
                int2 e = ovBuf[k];                 // (dst, src)
                if (e.x == d)
                    acc += dd * dinv[e.y] * (float)xw[(size_t)e.y * 128 + t];
            }
            h[(size_t)d * 128 + t] = (_Float16)(acc + conv_b[t]);
        }
        return;
    }
    // ---- sample role (128 blocks, one column each) ----
    __shared__ int hist[2048];
    __shared__ int wsum[4];
    const int c = blockIdx.x;
    for (int i = t; i < 2048; i += 256) hist[i] = 0;
    __syncthreads();
    const int ns = (n + 31) >> 5;
    for (int i = t; i < ns; i += 256) {
        float v = (float)h[(size_t)(i << 5) * 128 + c];
        atomicAdd(&hist[ordKey(v) >> 21], 1);
    }
    __syncthreads();
    int ps = 0;
    #pragma unroll
    for (int b = 0; b < 8; b++) ps += hist[t * 8 + b];
    const int lane = t & 63, wv = t >> 6;
    int sc = ps;
    #pragma unroll
    for (int off = 1; off < 64; off <<= 1) {
        int y = __shfl_up(sc, off, 64);
        if (lane >= off) sc += y;
    }
    if (lane == 63) wsum[wv] = sc;
    __syncthreads();
    int wbase = 0;
    for (int ww = 0; ww < wv; ww++) wbase += wsum[ww];
    const int excl = wbase + sc - ps;
    const int sMid = (ns - 1) >> 1;
    const int delta = (int)(4.0f * sqrtf((float)ns)) + 1;
    int sLo = sMid - delta; if (sLo < 0) sLo = 0;
    int sHi = sMid + delta; if (sHi > ns - 1) sHi = ns - 1;
    if (sLo >= excl && sLo < excl + ps) {
        int rem = sLo - excl, b = t * 8;
        for (;; b++) { int cc = hist[b]; if (rem < cc) break; rem -= cc; }
        Lkey[c] = (unsigned)b << 21;
    }
    if (sHi >= excl && sHi < excl + ps) {
        int rem = sHi - excl, b = t * 8;
        for (;; b++) { int cc = hist[b]; if (rem < cc) break; rem -= cc; }
        Ukey[c] = (((unsigned)(b + 1)) << 21) - 1u;
    }
}

// ---------------- classify: stream fp16 h, sharded below/cand flush -------
// 512 blocks; shard rid = blockIdx&7: atomic chains 512 -> 64 deep. Each
// column's cand space is 8 regions of RCAP (region r at col*CAP + r*RCAP).
__global__ __launch_bounds__(256) void k_classify(const _Float16* __restrict__ h,
                                                  int total8,
                                                  const unsigned* __restrict__ Lkey,
                                                  const unsigned* __restrict__ Ukey,
                                                  int* __restrict__ below8,
                                                  int* __restrict__ candCnt8,
                                                  _Float16* __restrict__ cand) {
    __shared__ _Float16 buf[128 * CSTR];  // 24.25 KB, stride 97 (bank-spread)
    __shared__ int cN[128], cB[128];
    const int t = threadIdx.x;
    const int rid = (int)blockIdx.x & (NREG - 1);
    for (int i = t; i < 128; i += 256) { cN[i] = 0; cB[i] = 0; }
    __syncthreads();
    const int stride = gridDim.x * blockDim.x;
    const int i0 = blockIdx.x * blockDim.x + t;
    const int jb = (i0 << 3) & 127;     // stride*8 % 128 == 0 -> invariant
    unsigned L[8], U[8];
    #pragma unroll
    for (int k = 0; k < 8; k++) { L[k] = Lkey[jb + k]; U[k] = Ukey[jb + k]; }
    int b[8] = {0, 0, 0, 0, 0, 0, 0, 0};
    const half8* hv = (const half8*)h;
    for (int i = i0; i < total8; i += stride) {
        half8 v = hv[i];
        #pragma unroll
        for (int k = 0; k < 8; k++) {
            float f = (float)v[k];
            unsigned u = ordKey(f);
            if (u < L[k]) b[k]++;
            else if (u <= U[k]) {
                int p = atomicAdd(&cN[jb + k], 1);
                if (p < CCAP) buf[(jb + k) * CSTR + p] = v[k];
                else {
                    int g = atomicAdd(&candCnt8[rid * 128 + jb + k], 1);
                    if (g < RCAP)
                        cand[(size_t)(jb + k) * CAP + rid * RCAP + g] = v[k];
                }
            }
        }
    }
    #pragma unroll
    for (int k = 0; k < 8; k++)
        if (b[k]) atomicAdd(&cB[jb + k], b[k]);
    __syncthreads();
    if (t < 128) {
        if (cB[t]) atomicAdd(&below8[rid * 128 + t], cB[t]);
        int nn = cN[t] < CCAP ? cN[t] : CCAP;
        if (nn) {
            int base = atomicAdd(&candCnt8[rid * 128 + t], nn);
            for (int k2 = 0; k2 < nn && base + k2 < RCAP; k2++)
                cand[(size_t)t * CAP + rid * RCAP + base + k2] = buf[t * CSTR + k2];
        }
    }
}

// ---------------- final: register-resident binary-search select + MLP -----
// 1024 threads, 8 regions x 3 slots = MPT 24 keys/thread (register-resident,
// no spill). 16 MSB-first iterations of count(<pivot). Greedy bit-build =
// exact r-th order statistic.
__global__ __launch_bounds__(1024) void k_finalMlp(
        const _Float16* __restrict__ cand, const int* __restrict__ candCnt8,
        const int* __restrict__ below8, int n, float* __restrict__ med,
        int* __restrict__ doneCnt,
        const float* __restrict__ w1, const float* __restrict__ b1,
        const float* __restrict__ w2, const float* __restrict__ b2,
        const float* __restrict__ w3, const float* __restrict__ b3,
        float* __restrict__ out) {
    __shared__ int wsum[16];
    __shared__ int lastFlag;
    const int c = blockIdx.x, t = threadIdx.x;
    const int lane = t & 63, wv = t >> 6;
    int below_tot = 0;
    #pragma unroll
    for (int rr = 0; rr < NREG; rr++) below_tot += below8[rr * 128 + c];
    int cnt = 0;
    unsigned short myk[MPT];
    const unsigned short* cbase = (const unsigned short*)cand + (size_t)c * CAP;
    #pragma unroll
    for (int rr = 0; rr < NREG; rr++) {
        int cr = candCnt8[rr * 128 + c]; if (cr > RCAP) cr = RCAP;
        cnt += cr;
        const unsigned short* rp = cbase + rr * RCAP;
        #pragma unroll
        for (int k = 0; k < RCAP / 1024; k++) {
            int i = t + k * 1024;
            unsigned ub = (i < cr) ? (unsigned)rp[i] : 0u;
            unsigned kk = (ub & 0x8000u) ? (~ub & 0xFFFFu) : (ub | 0x8000u);
            myk[rr * (RCAP / 1024) + k] =
                (i < cr) ? (unsigned short)kk : (unsigned short)0xFFFFu;
        }
    }
    int r = (n - 1) / 2 - below_tot;
    if (r < 0) r = 0;
    if (r >= cnt) r = cnt - 1;
    // 16-iteration binary search on the 16-bit ordered-key space
    unsigned cur = 0;
    for (int bit = 15; bit >= 0; bit--) {
        const unsigned pivot = cur | (1u << bit);
        int lc = 0;
        #pragma unroll
        for (int mi = 0; mi < MPT; mi++) lc += ((unsigned)myk[mi] < pivot) ? 1 : 0;
        #pragma unroll
        for (int off = 32; off > 0; off >>= 1) lc += __shfl_down(lc, off, 64);
        if (lane == 0) wsum[wv] = lc;
        __syncthreads();
        int tot = 0;
        #pragma unroll
        for (int ww = 0; ww < 16; ww++) tot += wsum[ww];
        if (tot <= r) cur = pivot;                 // uniform across block
        __syncthreads();
    }
    if (t == 0) {
        unsigned short bits = (cur & 0x8000u) ? (unsigned short)(cur & 0x7FFFu)
                                              : (unsigned short)(~cur & 0xFFFFu);
        _Float16 hv;
        *(unsigned short*)&hv = bits;
        med[c] = (float)hv;
        __threadfence();
        int old = atomicAdd(doneCnt, 1);
        lastFlag = (old == 127);
    }
    __syncthreads();
    if (!lastFlag) return;
    __threadfence();                                // acquire all med writes
    // ---- MLP role (one block) ----
    __shared__ float m[128], a1[64], a2[64];
    if (t < 128) m[t] = med[t];
    __syncthreads();
    if (t < 64) {
        float acc = b1[t];
        for (int f = 0; f < 128; f++) acc += m[f] * w1[t * 128 + f];
        a1[t] = tanhf(acc);
    }
    __syncthreads();
    if (t < 64) {
        float acc = b2[t];
        for (int f = 0; f < 64; f++) acc += a1[f] * w2[t * 64 + f];
        a2[t] = tanhf(acc);
    }
    __syncthreads();
    if (t == 0) {
        float acc = b3[0];
        for (int f = 0; f < 64; f++) acc += a2[f] * w3[f];
        out[0] = acc;
    }
}

extern "C" void kernel_launch(void* const* d_in, const int* in_sizes, int n_in,
                              void* d_out, int out_size, void* d_ws, size_t ws_size,
                              hipStream_t stream) {
    const float* x      = (const float*)d_in[0];
    const int*   ei     = (const int*)d_in[1];
    const float* conv_W = (const float*)d_in[2];
    const float* conv_b = (const float*)d_in[3];
    const float* w1 = (const float*)d_in[4];
    const float* b1 = (const float*)d_in[5];
    const float* w2 = (const float*)d_in[6];
    const float* b2 = (const float*)d_in[7];
    const float* w3 = (const float*)d_in[8];
    const float* b3 = (const float*)d_in[9];

    const int N = in_sizes[0] / 128;
    const int E = in_sizes[1] / 2;
    const int* src = ei;
    const int* dst = ei + E;
    const int NBK = (N + 255) / 256;

    char* p = (char*)d_ws;
    auto alloc = [&](size_t bytes) -> char* {
        char* q = p;
        p += (bytes + 255) & ~(size_t)255;
        return q;
    };
    _Float16* xw  = (_Float16*)alloc((size_t)N * 128 * 2);  // fp16
    _Float16* h   = (_Float16*)alloc((size_t)N * 128 * 2);  // fp16
    int2*  binned = (int2*)alloc((size_t)NBK * BCAP * 8);   // 14.4 MB; becomes adj
    _Float16* cand = (_Float16*)alloc((size_t)128 * CAP * 2);  // 6.3 MB fp16
    float* dinv   = (float*)alloc((size_t)N * 4);
    unsigned char* deg8 = (unsigned char*)alloc((size_t)N);
    int*   cursor = (int*)alloc((size_t)NBK * 4);
    short* Whi    = (short*)alloc(16384 * 2);
    short* Wlo    = (short*)alloc(16384 * 2);
    int2*  ovBuf  = (int2*)alloc((size_t)OVCAP * 8);
    int*   ovCnt  = (int*)alloc(256);             // [0]=ov, [1]=spill, [2]=done
    int*   spillNodes = (int*)alloc((size_t)SPCAP * 4);
    unsigned* Lkey = (unsigned*)alloc(128 * 4);
    unsigned* Ukey = (unsigned*)alloc(128 * 4);
    int*   below8   = (int*)alloc((size_t)NREG * 128 * 4);
    int*   candCnt8 = (int*)alloc((size_t)NREG * 128 * 4);
    float* med     = (float*)alloc(128 * 4);

    const int GB   = (N + 63) / 64;          // gemm blocks
    const int BINB = (E + CH - 1) / CH;      // bin blocks

    k_init<<<2, 256, 0, stream>>>(cursor, below8, candCnt8, ovCnt, conv_W,
                                  Whi, Wlo, NBK);
    k_binGemm<<<GB + BINB, 256, 0, stream>>>(x, Whi, Wlo, xw, N, GB,
                                             src, dst, E, cursor, binned,
                                             ovCnt, ovBuf, NBK);
    k_build<<<NBK, 1024, 0, stream>>>(binned, cursor, dinv, deg8, ovCnt, ovBuf,
                                      spillNodes, N);
    k_aggH<<<(N + 3) / 4, 256, 0, stream>>>(xw, deg8, (const int*)binned, dinv,
                                            conv_b, h, N);
    k_sampleSpill<<<144, 256, 0, stream>>>(h, N, Lkey, Ukey, xw, spillNodes,
                                           (const int*)binned, dinv, conv_b,
                                           ovBuf, ovCnt);
    k_classify<<<512, 256, 0, stream>>>(h, N * 16, Lkey, Ukey, below8, candCnt8,
                                        cand);
    k_finalMlp<<<128, 1024, 0, stream>>>(cand, candCnt8, below8, N, med,
                                         ovCnt + 2, w1, b1, w2, b2, w3, b3,
                                         (float*)d_out);
}